// Round 8
// baseline (278.372 us; speedup 1.0000x reference)
//
#include <hip/hip_runtime.h>

typedef __bf16 bf16x8 __attribute__((ext_vector_type(8)));
typedef __bf16 bf16x4 __attribute__((ext_vector_type(4)));
typedef float  f32x4  __attribute__((ext_vector_type(4)));

#define MFMA16(a, b, c) __builtin_amdgcn_mfma_f32_16x16x32_bf16(a, b, c, 0, 0, 0)
// async global->LDS, 16B per lane; LDS dest = wave-uniform base + lane*16
#define GLL(gp, lp) __builtin_amdgcn_global_load_lds( \
    (__attribute__((address_space(1))) void*)(gp),    \
    (__attribute__((address_space(3))) void*)(lp), 16, 0, 0)
// Barrier with manual vmcnt (keeps N GLLs in flight across the barrier) AND
// lgkmcnt(0) so queued ds_reads complete before buffers are overwritten.
#define WAITBAR(N) asm volatile("s_waitcnt vmcnt(" #N ") lgkmcnt(0)\n\ts_barrier" ::: "memory")

// ---------------- cast fp32 -> bf16 (vectorized) ----------------
__global__ __launch_bounds__(256) void cast_x_kernel(const float* __restrict__ in,
                                                     __bf16* __restrict__ out) {
  int i = blockIdx.x * 256 + threadIdx.x;
  const float4 v = ((const float4*)in)[i];
  bf16x4 o = {(__bf16)v.x, (__bf16)v.y, (__bf16)v.z, (__bf16)v.w};
  ((bf16x4*)out)[i] = o;
}

// ---------------- transpose + cast: out[n][k] = (bf16)in[k][n] ----------------
__global__ void transpose_cast_kernel(const float* __restrict__ in,
                                      __bf16* __restrict__ out,
                                      int rows, int cols) {
  __shared__ float tile[32][33];
  int tx = threadIdx.x, ty = threadIdx.y;
  int x = blockIdx.x * 32 + tx;
  int y0 = blockIdx.y * 32;
#pragma unroll
  for (int i = 0; i < 32; i += 8)
    tile[ty + i][tx] = in[(y0 + ty + i) * cols + x];
  __syncthreads();
  int ox = y0 + tx;
  int oy0 = blockIdx.x * 32;
#pragma unroll
  for (int i = 0; i < 32; i += 8)
    out[(oy0 + ty + i) * rows + ox] = (__bf16)tile[tx][ty + i];
}

// ---------------- GEMM: C[M,N] = A[M,1024] * Bt[N,1024]^T ----------------
// 128x128 tile, BK=32, 3-buffer depth-2 pipeline, WAITBAR(4).
// Flat grid + XCD swizzle: each XCD owns nx/8 consecutive n-tiles so its
// B-slice stays L2-resident while A streams.
#define QSCALE 0.045084220027780106f
__global__ __launch_bounds__(256) void gemm_bt_kernel(
    const __bf16* __restrict__ A, const __bf16* __restrict__ Bt, int mode, int nxg,
    __bf16* __restrict__ qo, __bf16* __restrict__ ko, __bf16* __restrict__ vo,
    float* __restrict__ outp, const float* __restrict__ bias) {
  __shared__ __bf16 LDS[3][2][4096];  // [buf][A/B][128*32] = 48 KiB
  const int tid = threadIdx.x;
  const int id = blockIdx.x;
  const int xcd = id & 7, s = id >> 3;
  const int bx = xcd * nxg + (nxg == 3 ? s % 3 : 0);
  const int by = (nxg == 3 ? s / 3 : s);
  const int m0 = by * 128, n0 = bx * 128;
  const int w = tid >> 6, lane = tid & 63;
  const int quad = lane >> 4, l15 = lane & 15;
  const int wm = (w >> 1) * 64, wn = (w & 1) * 64;
  f32x4 acc[4][4] = {};
  const int sr = tid >> 2;
  const int sc = (tid & 3) * 8;
  const __bf16* ag = A + (m0 + sr) * 1024 + sc;
  const __bf16* bg = Bt + (n0 + sr) * 1024 + sc;

  auto stage = [&](int T, int b) {
    const int kk = T * 32;
    GLL(ag + kk,             &LDS[b][0][0] + w * 512);
    GLL(ag + 64 * 1024 + kk, &LDS[b][0][0] + 2048 + w * 512);
    GLL(bg + kk,             &LDS[b][1][0] + w * 512);
    GLL(bg + 64 * 1024 + kk, &LDS[b][1][0] + 2048 + w * 512);
  };
  auto compute = [&](int b) {
    const __bf16* Asb = &LDS[b][0][0];
    const __bf16* Bsb = &LDS[b][1][0];
    bf16x8 af[4], bfr[4];
#pragma unroll
    for (int i = 0; i < 4; ++i)
      af[i] = *(const bf16x8*)(Asb + (wm + i * 16 + l15) * 32 + quad * 8);
#pragma unroll
    for (int j = 0; j < 4; ++j)
      bfr[j] = *(const bf16x8*)(Bsb + (wn + j * 16 + l15) * 32 + quad * 8);
#pragma unroll
    for (int i = 0; i < 4; ++i)
#pragma unroll
      for (int j = 0; j < 4; ++j)
        acc[i][j] = MFMA16(af[i], bfr[j], acc[i][j]);
  };

  // pipeline: tiles 0..31, tile t lives in buf t%3
  stage(0, 0);
  stage(1, 1);
  WAITBAR(4);                    // tile 0 ready (tile 1 still in flight)
  for (int g = 0; g < 10; ++g) {
    const int t = g * 3;
    stage(t + 2, 2); compute(0); WAITBAR(4);
    stage(t + 3, 0); compute(1); WAITBAR(4);
    stage(t + 4, 1); compute(2); WAITBAR(4);
  }
  compute(0);                    // tile 30
  asm volatile("s_waitcnt vmcnt(0) lgkmcnt(0)\n\ts_barrier" ::: "memory");
  compute(1);                    // tile 31
  __syncthreads();               // LDS free for epilogue scratch

  // ---- epilogue ----
  const int gcw = n0 + wn;       // wave's 64-col base (one tensor, one head)
  float* T = (float*)(&LDS[0][0][0]) + w * 1088;  // per-wave [16][68] f32
  if (mode == 0) {
    const int which = gcw >> 10;
    const int h = (gcw & 1023) >> 6;
    if (which == 2) {
      // V: acc rows = consecutive tokens => packed bf16x4 stores into vt[.][d][n]
#pragma unroll
      for (int i = 0; i < 4; ++i) {
        int gm = m0 + wm + i * 16 + quad * 4;
        int b = gm >> 10, n = gm & 1023;
        __bf16* vb = vo + ((long)(b * 16 + h) * 64) * 1024 + n;
#pragma unroll
        for (int j = 0; j < 4; ++j) {
          int dd = j * 16 + l15;
          bf16x4 pv = {(__bf16)acc[i][j][0], (__bf16)acc[i][j][1],
                       (__bf16)acc[i][j][2], (__bf16)acc[i][j][3]};
          *(bf16x4*)(vb + (long)dd * 1024) = pv;
        }
      }
    } else {
      // Q/K: LDS transpose -> 16B coalesced stores
      __bf16* dst = (which == 0) ? qo : ko;
      const float scl = (which == 0) ? QSCALE : 1.0f;
#pragma unroll
      for (int i = 0; i < 4; ++i) {
#pragma unroll
        for (int j = 0; j < 4; ++j)
#pragma unroll
          for (int r = 0; r < 4; ++r)
            T[(quad * 4 + r) * 68 + j * 16 + l15] = acc[i][j][r];
        const float* Tr = T + l15 * 68 + quad * 16;
        f32x4 c0 = *(const f32x4*)(Tr);
        f32x4 c1 = *(const f32x4*)(Tr + 4);
        f32x4 c2 = *(const f32x4*)(Tr + 8);
        f32x4 c3 = *(const f32x4*)(Tr + 12);
        int gm = m0 + wm + i * 16 + l15;
        int b = gm >> 10, n = gm & 1023;
        __bf16* p = dst + ((long)((b * 16 + h) * 1024 + n)) * 64 + quad * 16;
        bf16x8 o0 = {(__bf16)(c0[0] * scl), (__bf16)(c0[1] * scl),
                     (__bf16)(c0[2] * scl), (__bf16)(c0[3] * scl),
                     (__bf16)(c1[0] * scl), (__bf16)(c1[1] * scl),
                     (__bf16)(c1[2] * scl), (__bf16)(c1[3] * scl)};
        bf16x8 o1 = {(__bf16)(c2[0] * scl), (__bf16)(c2[1] * scl),
                     (__bf16)(c2[2] * scl), (__bf16)(c2[3] * scl),
                     (__bf16)(c3[0] * scl), (__bf16)(c3[1] * scl),
                     (__bf16)(c3[2] * scl), (__bf16)(c3[3] * scl)};
        *(bf16x8*)p = o0;
        *(bf16x8*)(p + 8) = o1;
      }
    }
  } else {
    // out-proj: LDS transpose -> f32x4 stores + bias
    const int cb = gcw;
    f32x4 bv[4];
#pragma unroll
    for (int c = 0; c < 4; ++c)
      bv[c] = *(const f32x4*)(bias + cb + quad * 16 + c * 4);
#pragma unroll
    for (int i = 0; i < 4; ++i) {
#pragma unroll
      for (int j = 0; j < 4; ++j)
#pragma unroll
        for (int r = 0; r < 4; ++r)
          T[(quad * 4 + r) * 68 + j * 16 + l15] = acc[i][j][r];
      const float* Tr = T + l15 * 68 + quad * 16;
      int gm = m0 + wm + i * 16 + l15;
      float* p = outp + (long)gm * 1024 + cb + quad * 16;
#pragma unroll
      for (int c = 0; c < 4; ++c) {
        f32x4 v = *(const f32x4*)(Tr + c * 4);
        v += bv[c];
        *(f32x4*)(p + c * 4) = v;
      }
    }
  }
}

// ---------------- attention v3: 64 Q-rows/wave, prefetched staging ----------------
// grid: 512 blocks (bh = blk & 127 -> XCD-local; qt = blk >> 7, 256 rows/block).
// Per wave: 4 i-frags (64 rows). K/V staged per 128-j tile; next tile's K/V
// loaded into registers right after the ready-barrier (overlaps compute).
// Q-quarter interleave: QK -> exp2 -> P(LDS, stride 40) -> PV per 32 j.
__global__ __launch_bounds__(256, 2) void attn_kernel(
    const __bf16* __restrict__ q, const __bf16* __restrict__ k,
    const __bf16* __restrict__ vt, __bf16* __restrict__ ao) {
  __shared__ __bf16 Ks[128 * 64];    // [j][d], granule g -> g ^ (j&7)
  __shared__ __bf16 Vs[64 * 128];    // [d][j], granule g -> g ^ (d&15)
  __shared__ __bf16 Ps[4][64 * 40];  // per-wave P quarter [i=64][j=32], stride 40
  const int tid = threadIdx.x;
  const int bh = blockIdx.x & 127, qt = blockIdx.x >> 7;
  const int w = tid >> 6, lane = tid & 63;
  const int quad = lane >> 4, l15 = lane & 15;
  const int qrow = qt * 256 + w * 64;
  bf16x8 qf[4][2];
#pragma unroll
  for (int f = 0; f < 4; ++f) {
    const __bf16* qb = q + ((long)(bh * 1024 + qrow + f * 16 + l15)) * 64;
    qf[f][0] = *(const bf16x8*)(qb + quad * 8);
    qf[f][1] = *(const bf16x8*)(qb + 32 + quad * 8);
  }
  f32x4 o[4][4] = {};
  float rs[4] = {0.f, 0.f, 0.f, 0.f};
  const int krow = tid >> 3, kg8 = tid & 7;
  const __bf16* kg = k + (bh * 1024 + krow) * 64 + kg8 * 8;
  const int ksw = (kg8 ^ (krow & 7)) * 8;
  const int vrow = tid >> 2, vg4 = tid & 3;
  const __bf16* vg = vt + (bh * 64 + vrow) * 1024 + vg4 * 8;
  const int kfs0 = (quad ^ (l15 & 7)) * 8;
  const int kfs1 = ((4 + quad) ^ (l15 & 7)) * 8;
  __bf16* pw = Ps[w];
  bf16x8 kv[4], vv[4];
#pragma unroll
  for (int p = 0; p < 4; ++p) kv[p] = *(const bf16x8*)(kg + (p * 32) * 64);
#pragma unroll
  for (int p = 0; p < 4; ++p) vv[p] = *(const bf16x8*)(vg + p * 32);
  for (int j0 = 0; j0 < 1024; j0 += 128) {
    __syncthreads();   // all waves done reading previous tiles
#pragma unroll
    for (int p = 0; p < 4; ++p)
      *(bf16x8*)(Ks + (krow + p * 32) * 64 + ksw) = kv[p];
#pragma unroll
    for (int p = 0; p < 4; ++p)
      *(bf16x8*)(Vs + vrow * 128 + (((p * 4 + vg4) ^ (vrow & 15)) * 8)) = vv[p];
    __syncthreads();   // tiles ready
    if (j0 + 128 < 1024) {  // prefetch next tile; overlaps the compute below
#pragma unroll
      for (int p = 0; p < 4; ++p) kv[p] = *(const bf16x8*)(kg + (j0 + 128 + p * 32) * 64);
#pragma unroll
      for (int p = 0; p < 4; ++p) vv[p] = *(const bf16x8*)(vg + j0 + 128 + p * 32);
    }
#pragma unroll
    for (int Q = 0; Q < 4; ++Q) {
#pragma unroll
      for (int tl = 0; tl < 2; ++tl) {
        const int t = 2 * Q + tl;
        const __bf16* kr = Ks + (t * 16 + l15) * 64;
        bf16x8 kf0 = *(const bf16x8*)(kr + kfs0);
        bf16x8 kf1 = *(const bf16x8*)(kr + kfs1);
#pragma unroll
        for (int f = 0; f < 4; ++f) {
          f32x4 z = {};
          z = MFMA16(kf0, qf[f][0], z);
          z = MFMA16(kf1, qf[f][1], z);
          float p0 = exp2f(z[0]), p1 = exp2f(z[1]), p2 = exp2f(z[2]), p3 = exp2f(z[3]);
          rs[f] += (p0 + p1) + (p2 + p3);
          *(bf16x4*)(pw + (f * 16 + l15) * 40 + tl * 16 + quad * 4) =
              (bf16x4){(__bf16)p0, (__bf16)p1, (__bf16)p2, (__bf16)p3};
        }
      }
      bf16x8 pf[4];
#pragma unroll
      for (int f = 0; f < 4; ++f)
        pf[f] = *(const bf16x8*)(pw + (f * 16 + l15) * 40 + quad * 8);
#pragma unroll
      for (int dt = 0; dt < 4; ++dt) {
        bf16x8 vf = *(const bf16x8*)(Vs + (dt * 16 + l15) * 128 + (((Q * 4 + quad) ^ l15) * 8));
#pragma unroll
        for (int f = 0; f < 4; ++f)
          o[f][dt] = MFMA16(pf[f], vf, o[f][dt]);
      }
    }
  }
#pragma unroll
  for (int f = 0; f < 4; ++f) {
    rs[f] += __shfl_xor(rs[f], 16);
    rs[f] += __shfl_xor(rs[f], 32);
  }
  const int b = bh >> 4, h = bh & 15;
  const int qbase = quad << 4;
#pragma unroll
  for (int f = 0; f < 4; ++f)
#pragma unroll
    for (int r = 0; r < 4; ++r) {
      int src = qbase | (quad * 4 + r);
      float inv = 1.0f / __shfl(rs[f], src);
      long row = b * 1024 + qrow + f * 16 + quad * 4 + r;
#pragma unroll
      for (int dt = 0; dt < 4; ++dt)
        ao[row * 1024 + h * 64 + dt * 16 + l15] = (__bf16)(o[f][dt][r] * inv);
    }
}

// ---------------- launch ----------------
extern "C" void kernel_launch(void* const* d_in, const int* in_sizes, int n_in,
                              void* d_out, int out_size, void* d_ws, size_t ws_size,
                              hipStream_t stream) {
  const float* x = (const float*)d_in[0];      // [8192,1024]
  const float* w_qkv = (const float*)d_in[1];  // [1024,3072]
  const float* w_out = (const float*)d_in[2];  // [1024,1024]
  const float* b_out = (const float*)d_in[3];  // [1024]
  float* out = (float*)d_out;

  char* ws = (char*)d_ws;
  __bf16* xb    = (__bf16*)(ws);                 // 16 MiB
  __bf16* wqkvt = (__bf16*)(ws + 16777216);      // 6 MiB
  __bf16* woutt = (__bf16*)(ws + 23068672);      // 2 MiB
  __bf16* qw    = (__bf16*)(ws + 25165824);
  __bf16* kw    = (__bf16*)(ws + 41943040);
  __bf16* vw    = (__bf16*)(ws + 58720256);      // end = 75497472
  __bf16* ao    = xb;  // alias: xb dead after QKV GEMM

  cast_x_kernel<<<8192, 256, 0, stream>>>(x, xb);
  transpose_cast_kernel<<<dim3(96, 32), dim3(32, 8), 0, stream>>>(w_qkv, wqkvt, 1024, 3072);
  transpose_cast_kernel<<<dim3(32, 32), dim3(32, 8), 0, stream>>>(w_out, woutt, 1024, 1024);
  gemm_bt_kernel<<<1536, 256, 0, stream>>>(xb, wqkvt, 0, 3, qw, kw, vw, nullptr, nullptr);
  attn_kernel<<<512, 256, 0, stream>>>(qw, kw, vw, ao);
  gemm_bt_kernel<<<512, 256, 0, stream>>>(ao, woutt, 1, 1, nullptr, nullptr, nullptr, out, b_out);
}